// Round 1
// baseline (706.544 us; speedup 1.0000x reference)
//
#include <hip/hip_runtime.h>

// ---------------------------------------------------------------------------
// Fused Linear + SimPO loss on MI355X (gfx950)
// M = B2*T = 4096 tokens, V = 32000 vocab, H(K) = 2048
// loss = ALPHA * chosen_nll + mean_b(-log_sigmoid(BETA*(c_b - r_b) - GAMMA))
// ---------------------------------------------------------------------------

typedef short bf16x8 __attribute__((ext_vector_type(8)));   // 8 bf16 = 4 VGPRs
typedef float f32x4 __attribute__((ext_vector_type(4)));

#define IGNORE_INDEX (-100)
#define BETA_ 0.1f
#define GAMMA_ 0.5f

#define M_TOK 4096
#define V_DIM 32000
#define K_DIM 2048
#define NVT 250          // V / 128
#define NMT 32           // M / 128

__device__ inline unsigned short f2bf(float f) {   // RNE fp32 -> bf16
    unsigned u = __float_as_uint(f);
    return (unsigned short)((u + 0x7FFFu + ((u >> 16) & 1u)) >> 16);
}

// -------- fp32 -> bf16 conversion, 4 elems/thread, exact-size grid ---------
__global__ void __launch_bounds__(256) cvt_kernel(const float* __restrict__ src,
                                                  unsigned short* __restrict__ dst) {
    size_t i = ((size_t)blockIdx.x * 256 + threadIdx.x) * 4;
    float4 v = *reinterpret_cast<const float4*>(src + i);
    ushort4 o;
    o.x = f2bf(v.x); o.y = f2bf(v.y); o.z = f2bf(v.z); o.w = f2bf(v.w);
    *reinterpret_cast<ushort4*>(dst + i) = o;
}

// -------- exact fp32 target logit: one wave per token ----------------------
__global__ void __launch_bounds__(256) zt_kernel(const float* __restrict__ X,
                                                 const float* __restrict__ W,
                                                 const float* __restrict__ bias,
                                                 const int* __restrict__ target,
                                                 float* __restrict__ zt) {
    int token = blockIdx.x * 4 + (threadIdx.x >> 6);
    int lane = threadIdx.x & 63;
    int t = target[token];
    int tt = (t < 0) ? 0 : t;                       // masked tokens: value unused
    const float4* xr = reinterpret_cast<const float4*>(X + (size_t)token * K_DIM);
    const float4* wr = reinterpret_cast<const float4*>(W + (size_t)tt * K_DIM);
    float s = 0.f;
    #pragma unroll
    for (int j = 0; j < 8; ++j) {                   // 2048/4/64 = 8
        float4 a = xr[lane + j * 64];
        float4 b = wr[lane + j * 64];
        s += a.x * b.x + a.y * b.y + a.z * b.z + a.w * b.w;
    }
    #pragma unroll
    for (int m = 1; m < 64; m <<= 1) s += __shfl_xor(s, m, 64);
    if (lane == 0) zt[token] = s + bias[tt];
}

// -------- bf16 NT GEMM (m97 structure) with fused sum-exp epilogue ---------
// grid = NMT * NVT blocks, 256 threads (4 waves, 2x2, each wave 64x64 out)
#define GLL(g, l) __builtin_amdgcn_global_load_lds( \
    (const __attribute__((address_space(1))) void*)(g), \
    (__attribute__((address_space(3))) void*)(l), 16, 0, 0)

__global__ void __launch_bounds__(256) gemm_lse_kernel(
    const unsigned short* __restrict__ Xb,   // [4096][2048] bf16
    const unsigned short* __restrict__ Wb,   // [32000][2048] bf16
    const float* __restrict__ bias,          // [32000]
    float* __restrict__ partials) {          // [NVT][4096] sum-exp partials
    __shared__ unsigned short lsA[128 * 32]; // 8 KB
    __shared__ unsigned short lsB[128 * 32]; // 8 KB

    const int tid = threadIdx.x;
    const int wid = tid >> 6;
    const int lane = tid & 63;
    const int mt = blockIdx.x & 31;          // M-tile fastest: same-vt blocks adjacent
    const int vt = blockIdx.x >> 5;
    const int wrow = wid >> 1, wcol = wid & 1;
    const int g = lane >> 4, r = lane & 15;

    // staging sources: flat byte tid*16 of the [128][32] bf16 tile
    const unsigned short* aS0 = Xb + (size_t)(mt * 128 + (tid >> 2)) * K_DIM + (tid & 3) * 8;
    const unsigned short* aS1 = aS0 + 64 * K_DIM;
    const unsigned short* bS0 = Wb + (size_t)(vt * 128 + (tid >> 2)) * K_DIM + (tid & 3) * 8;
    const unsigned short* bS1 = bS0 + 64 * K_DIM;
    char* ldA0 = (char*)lsA + wid * 1024;    // wave-uniform LDS bases
    char* ldA1 = ldA0 + 4096;
    char* ldB0 = (char*)lsB + wid * 1024;
    char* ldB1 = ldB0 + 4096;

    const unsigned short* fA = lsA + (wrow * 64 + r) * 32 + g * 8;
    const unsigned short* fB = lsB + (wcol * 64 + r) * 32 + g * 8;

    f32x4 acc[4][4] = {};

    for (int ks = 0; ks < K_DIM / 32; ++ks) {
        __syncthreads();
        GLL(aS0, ldA0); GLL(aS1, ldA1);
        GLL(bS0, ldB0); GLL(bS1, ldB1);
        aS0 += 32; aS1 += 32; bS0 += 32; bS1 += 32;
        __syncthreads();
        bf16x8 af[4], bf[4];
        #pragma unroll
        for (int mi = 0; mi < 4; ++mi)
            af[mi] = *reinterpret_cast<const bf16x8*>(fA + mi * 16 * 32);
        #pragma unroll
        for (int ni = 0; ni < 4; ++ni)
            bf[ni] = *reinterpret_cast<const bf16x8*>(fB + ni * 16 * 32);
        #pragma unroll
        for (int mi = 0; mi < 4; ++mi)
            #pragma unroll
            for (int ni = 0; ni < 4; ++ni)
                acc[mi][ni] = __builtin_amdgcn_mfma_f32_16x16x32_bf16(
                    af[mi], bf[ni], acc[mi][ni], 0, 0, 0);
    }

    // ---- epilogue: bias + exp + row-sum over this block's 128 columns ----
    // C/D layout (m89): col = lane&15, row = (lane>>4)*4 + reg
    float bb[4];
    #pragma unroll
    for (int ni = 0; ni < 4; ++ni)
        bb[ni] = bias[vt * 128 + wcol * 64 + ni * 16 + r];

    __syncthreads();                         // safe to reuse lsA
    float* red = reinterpret_cast<float*>(lsA);  // [2 wavecols][128 rows]
    #pragma unroll
    for (int mi = 0; mi < 4; ++mi) {
        #pragma unroll
        for (int i = 0; i < 4; ++i) {
            float s = 0.f;
            #pragma unroll
            for (int ni = 0; ni < 4; ++ni)
                s += __expf(acc[mi][ni][i] + bb[ni]);
            s += __shfl_xor(s, 1, 64);
            s += __shfl_xor(s, 2, 64);
            s += __shfl_xor(s, 4, 64);
            s += __shfl_xor(s, 8, 64);       // sum over 16 cols (within group)
            if (r == 0) red[wcol * 128 + wrow * 64 + mi * 16 + g * 4 + i] = s;
        }
    }
    __syncthreads();
    if (tid < 128) {
        float tot = red[tid] + red[128 + tid];
        partials[(size_t)vt * M_TOK + mt * 128 + tid] = tot;
    }
}

// -------- combine partials -> per-token logp -------------------------------
__global__ void __launch_bounds__(256) lse_kernel(const float* __restrict__ partials,
                                                  const float* __restrict__ zt,
                                                  float* __restrict__ logp) {
    int token = blockIdx.x * 256 + threadIdx.x;   // 16 blocks
    float s = 0.f;
    for (int v = 0; v < NVT; ++v) s += partials[(size_t)v * M_TOK + token];
    logp[token] = zt[token] - logf(s);
}

// -------- final SimPO scalar ----------------------------------------------
__global__ void __launch_bounds__(512) loss_kernel(const float* __restrict__ logp,
                                                   const int* __restrict__ target,
                                                   float* __restrict__ out) {
    __shared__ float ss[8], sc[8];
    int wid = threadIdx.x >> 6, lane = threadIdx.x & 63;
    float s = 0.f, cnt = 0.f;
    #pragma unroll
    for (int j = 0; j < 8; ++j) {
        int token = wid * 512 + lane + j * 64;
        if (target[token] != IGNORE_INDEX) { s += logp[token]; cnt += 1.f; }
    }
    #pragma unroll
    for (int m = 1; m < 64; m <<= 1) {
        s += __shfl_xor(s, m, 64);
        cnt += __shfl_xor(cnt, m, 64);
    }
    if (lane == 0) { ss[wid] = s; sc[wid] = cnt; }
    __syncthreads();
    if (threadIdx.x == 0) {
        float csum = 0.f, ccnt = 0.f;
        for (int b = 0; b < 4; ++b) { csum += ss[b]; ccnt += sc[b]; }
        float nll = -csum / ccnt;
        float pref = 0.f;
        for (int b = 0; b < 4; ++b) {
            float d = BETA_ * (ss[b] / sc[b] - ss[b + 4] / sc[b + 4]) - GAMMA_;
            // -log_sigmoid(d) = softplus(-d)
            float sp = (d > 0.f) ? log1pf(expf(-d)) : (-d + log1pf(expf(d)));
            pref += sp;
        }
        pref *= 0.25f;                        // / half
        out[0] = nll + pref;                  // ALPHA = 1
    }
}

// ---------------------------------------------------------------------------
extern "C" void kernel_launch(void* const* d_in, const int* in_sizes, int n_in,
                              void* d_out, int out_size, void* d_ws, size_t ws_size,
                              hipStream_t stream) {
    const float* W    = (const float*)d_in[0];   // [32000][2048]
    const float* X    = (const float*)d_in[1];   // [8][512][2048]
    const int* target = (const int*)d_in[2];     // [4096]
    const float* bias = (const float*)d_in[3];   // [32000]
    float* out = (float*)d_out;
    char* ws = (char*)d_ws;

    // workspace layout (all 16B aligned), ~152 MB total
    unsigned short* Wb = (unsigned short*)(ws);                    // 131,072,000 B
    unsigned short* Xb = (unsigned short*)(ws + 131072000);        //  16,777,216 B
    float* partials    = (float*)(ws + 147849216);                 //   4,096,000 B
    float* zt          = (float*)(ws + 151945216);                 //      16,384 B
    float* logp        = (float*)(ws + 151961600);                 //      16,384 B

    cvt_kernel<<<dim3(64000), 256, 0, stream>>>(W, Wb);            // 65,536,000 elems
    cvt_kernel<<<dim3(8192), 256, 0, stream>>>(X, Xb);             //  8,388,608 elems
    zt_kernel<<<dim3(1024), 256, 0, stream>>>(X, W, bias, target, zt);
    gemm_lse_kernel<<<dim3(NMT * NVT), 256, 0, stream>>>(Xb, Wb, bias, partials);
    lse_kernel<<<dim3(16), 256, 0, stream>>>(partials, zt, logp);
    loss_kernel<<<dim3(1), 512, 0, stream>>>(logp, target, out);
}

// Round 3
// 614.183 us; speedup vs baseline: 1.1504x; 1.1504x over previous
//
#include <hip/hip_runtime.h>

// ---------------------------------------------------------------------------
// Fused Linear + SimPO loss on MI355X (gfx950)
// M = 4096 tokens, V = 32000, K = 2048
// GEMM: 256x256 tile, BK=64, 8 waves, 8-phase schedule, counted vmcnt,
// T2 LDS swizzle (both-sides), T5 setprio, fused sum-exp epilogue.
// Round-3 fix: no global_load_lds offset immediate — laundered ks1 pointers.
// ---------------------------------------------------------------------------

typedef short bf16x8 __attribute__((ext_vector_type(8)));
typedef float f32x4 __attribute__((ext_vector_type(4)));

#define IGNORE_INDEX (-100)
#define BETA_ 0.1f
#define GAMMA_ 0.5f

#define M_TOK 4096
#define V_DIM 32000
#define K_DIM 2048
#define NVT 125          // V / 256
#define NMT 16           // M / 256
#define NT  32           // K / 64  (K-tiles)

__device__ inline unsigned short f2bf(float f) {   // RNE fp32 -> bf16
    unsigned u = __float_as_uint(f);
    return (unsigned short)((u + 0x7FFFu + ((u >> 16) & 1u)) >> 16);
}

// -------- fp32 -> bf16 conversion ------------------------------------------
__global__ void __launch_bounds__(256) cvt_kernel(const float* __restrict__ src,
                                                  unsigned short* __restrict__ dst) {
    size_t i = ((size_t)blockIdx.x * 256 + threadIdx.x) * 4;
    float4 v = *reinterpret_cast<const float4*>(src + i);
    ushort4 o;
    o.x = f2bf(v.x); o.y = f2bf(v.y); o.z = f2bf(v.z); o.w = f2bf(v.w);
    *reinterpret_cast<ushort4*>(dst + i) = o;
}

// -------- exact fp32 target logit: one wave per token ----------------------
__global__ void __launch_bounds__(256) zt_kernel(const float* __restrict__ X,
                                                 const float* __restrict__ W,
                                                 const float* __restrict__ bias,
                                                 const int* __restrict__ target,
                                                 float* __restrict__ zt) {
    int token = blockIdx.x * 4 + (threadIdx.x >> 6);
    int lane = threadIdx.x & 63;
    int t = target[token];
    int tt = (t < 0) ? 0 : t;
    const float4* xr = reinterpret_cast<const float4*>(X + (size_t)token * K_DIM);
    const float4* wr = reinterpret_cast<const float4*>(W + (size_t)tt * K_DIM);
    float s = 0.f;
    #pragma unroll
    for (int j = 0; j < 8; ++j) {
        float4 a = xr[lane + j * 64];
        float4 b = wr[lane + j * 64];
        s += a.x * b.x + a.y * b.y + a.z * b.z + a.w * b.w;
    }
    #pragma unroll
    for (int m = 1; m < 64; m <<= 1) s += __shfl_xor(s, m, 64);
    if (lane == 0) zt[token] = s + bias[tt];
}

// -------- 256^2 8-phase bf16 GEMM with fused sum-exp epilogue --------------
// LDS per buffer (stride 65536): A_ks0 @0, A_ks1 @16384, B_ks0 @32768,
// B_ks1 @49152. Region = [256 rows][32 k-elems] bf16, row stride 64B.
// Swizzle: 16B slot c of row holds global k-slot (c ^ (row&3)).
#define GLL(g, l) __builtin_amdgcn_global_load_lds( \
    (const __attribute__((address_space(1))) void*)(g), \
    (__attribute__((address_space(3))) void*)(l), 16, 0, 0)

__global__ void __launch_bounds__(512, 2) gemm_lse_kernel(
    const unsigned short* __restrict__ Xb,   // [4096][2048] bf16
    const unsigned short* __restrict__ Wb,   // [32000][2048] bf16
    const float* __restrict__ bias,          // [32000]
    float* __restrict__ partials) {          // [NVT][4096] sum-exp partials
    __shared__ char lds[131072];

    const int tid = threadIdx.x;
    const int wid = tid >> 6;
    const int lane = tid & 63;
    const int r = lane & 15, g = lane >> 4;
    const int wm = wid >> 2, wn = wid & 3;

    // bijective XCD-chunked swizzle: 2000 = 8 * 250, mt fastest inside chunk
    int nb = (blockIdx.x & 7) * 250 + (blockIdx.x >> 3);
    const int vt = nb >> 4;
    const int mt = nb & 15;

    // staging: thread covers row (tid>>2) (+128 for *S1), 16B slot tid&3,
    // inverse-swizzled source slot = (tid&3) ^ (row&3)
    const int srow = tid >> 2;
    const int scol = ((tid & 3) ^ (srow & 3)) * 8;
    const unsigned short* aS0 = Xb + (size_t)(mt * 256 + srow) * K_DIM + scol;
    const unsigned short* aS1 = aS0 + (size_t)128 * K_DIM;
    const unsigned short* bS0 = Wb + (size_t)(vt * 256 + srow) * K_DIM + scol;
    const unsigned short* bS1 = bS0 + (size_t)128 * K_DIM;
    // dedicated ks1 pointers (+32 elems), laundered so the compiler cannot
    // fold the +64B into a global_load_lds offset immediate
    const unsigned short* aS0k = aS0 + 32;
    const unsigned short* aS1k = aS1 + 32;
    const unsigned short* bS0k = bS0 + 32;
    const unsigned short* bS1k = bS1 + 32;
    asm volatile("" : "+v"(aS0k), "+v"(aS1k), "+v"(bS0k), "+v"(bS1k));

    char* sbase = lds + wid * 1024;          // wave-uniform staging base
    // swizzled ds_read per-lane byte offsets
    const int vA = (wm * 128 + r) * 64 + ((g ^ (r & 3)) << 4);
    const int vB = (wn * 64 + r) * 64 + ((g ^ (r & 3)) << 4);

    f32x4 acc[8][4] = {};
    bf16x8 af[8], b0, b1;
    int pb = 0;

    // ---- prologue: tile0 (all 4 regions) into buf0, tile1 ks0 into buf1 ----
    GLL(aS0, sbase + 0);              GLL(aS1, sbase + 8192);
    GLL(bS0, sbase + 32768);          GLL(bS1, sbase + 32768 + 8192);
    GLL(aS0k, sbase + 16384);         GLL(aS1k, sbase + 16384 + 8192);
    GLL(bS0k, sbase + 49152);         GLL(bS1k, sbase + 49152 + 8192);
    aS0 += 64; aS1 += 64; bS0 += 64; bS1 += 64;
    aS0k += 64; aS1k += 64; bS0k += 64; bS1k += 64;
    GLL(aS0, sbase + 65536);          GLL(aS1, sbase + 65536 + 8192);
    GLL(bS0, sbase + 65536 + 32768);  GLL(bS1, sbase + 65536 + 32768 + 8192);
    asm volatile("s_waitcnt vmcnt(4)" ::: "memory");
    __builtin_amdgcn_s_barrier();

#define PH_READS_A(ks) \
    _Pragma("unroll") \
    for (int mf = 0; mf < 8; ++mf) \
        af[mf] = *(const bf16x8*)(lds + pb + vA + (ks) * 16384 + mf * 1024);

#define PH_READS_B(ks, nfb) \
    b0 = *(const bf16x8*)(lds + pb + vB + 32768 + (ks) * 16384 + (nfb) * 1024); \
    b1 = *(const bf16x8*)(lds + pb + vB + 32768 + (ks) * 16384 + ((nfb) + 1) * 1024);

#define PH_MFMA(nfb) \
    __builtin_amdgcn_s_setprio(1); \
    _Pragma("unroll") \
    for (int mf = 0; mf < 8; ++mf) { \
        acc[mf][(nfb)]     = __builtin_amdgcn_mfma_f32_16x16x32_bf16(af[mf], b0, acc[mf][(nfb)], 0, 0, 0); \
        acc[mf][(nfb) + 1] = __builtin_amdgcn_mfma_f32_16x16x32_bf16(af[mf], b1, acc[mf][(nfb) + 1], 0, 0, 0); \
    } \
    __builtin_amdgcn_s_setprio(0);

#define LGKM0 asm volatile("s_waitcnt lgkmcnt(0)" ::: "memory")

// Per K-tile body. I12: stage (t+1) ks1 into other buffer.
// I34: stage (t+2) ks0 into current buffer. DRAIN_STMT at end of P4.
#define KBODY(I12, I34, DRAIN_STMT) do { \
    char* cb = sbase + pb; \
    char* ob = sbase + (pb ^ 65536); \
    /* P1 */ \
    PH_READS_A(0); PH_READS_B(0, 0); \
    if (I12) { GLL(aS0k, ob + 16384); GLL(aS1k, ob + 16384 + 8192); } \
    __builtin_amdgcn_s_barrier(); \
    LGKM0; \
    PH_MFMA(0); \
    __builtin_amdgcn_s_barrier(); \
    /* P2 */ \
    PH_READS_B(0, 2); \
    if (I12) { GLL(bS0k, ob + 49152); GLL(bS1k, ob + 49152 + 8192); } \
    __builtin_amdgcn_s_barrier(); \
    LGKM0; \
    PH_MFMA(2); \
    __builtin_amdgcn_s_barrier(); \
    aS0 += 64; aS1 += 64; bS0 += 64; bS1 += 64; \
    aS0k += 64; aS1k += 64; bS0k += 64; bS1k += 64; \
    /* P3 */ \
    PH_READS_A(1); PH_READS_B(1, 0); \
    if (I34) { GLL(aS0, cb); GLL(aS1, cb + 8192); } \
    __builtin_amdgcn_s_barrier(); \
    LGKM0; \
    PH_MFMA(0); \
    __builtin_amdgcn_s_barrier(); \
    /* P4 */ \
    PH_READS_B(1, 2); \
    if (I34) { GLL(bS0, cb + 32768); GLL(bS1, cb + 32768 + 8192); } \
    __builtin_amdgcn_s_barrier(); \
    LGKM0; \
    PH_MFMA(2); \
    DRAIN_STMT; \
    __builtin_amdgcn_s_barrier(); \
    pb ^= 65536; \
} while (0)

    #pragma unroll 1
    for (int t = 0; t < NT - 2; ++t)
        KBODY(1, 1, asm volatile("s_waitcnt vmcnt(4)" ::: "memory"));
    KBODY(1, 0, asm volatile("s_waitcnt vmcnt(0)" ::: "memory"));
    KBODY(0, 0, (void)0);

    // ---- epilogue: bias + exp + row-sum over 256 cols --------------------
    float bb[4];
    #pragma unroll
    for (int nf = 0; nf < 4; ++nf)
        bb[nf] = bias[vt * 256 + wn * 64 + nf * 16 + r];

    __syncthreads();
    float* red = reinterpret_cast<float*>(lds);  // [4 wn][256 rows]
    #pragma unroll
    for (int mf = 0; mf < 8; ++mf) {
        #pragma unroll
        for (int i = 0; i < 4; ++i) {
            float s = 0.f;
            #pragma unroll
            for (int nf = 0; nf < 4; ++nf)
                s += __expf(acc[mf][nf][i] + bb[nf]);
            s += __shfl_xor(s, 1, 64);
            s += __shfl_xor(s, 2, 64);
            s += __shfl_xor(s, 4, 64);
            s += __shfl_xor(s, 8, 64);
            if (r == 0) red[wn * 256 + wm * 128 + mf * 16 + g * 4 + i] = s;
        }
    }
    __syncthreads();
    if (tid < 256) {
        float tot = red[tid] + red[256 + tid] + red[512 + tid] + red[768 + tid];
        partials[(size_t)vt * M_TOK + mt * 256 + tid] = tot;
    }
}

// -------- combine partials -> per-token logp -------------------------------
__global__ void __launch_bounds__(256) lse_kernel(const float* __restrict__ partials,
                                                  const float* __restrict__ zt,
                                                  float* __restrict__ logp) {
    int token = blockIdx.x * 256 + threadIdx.x;
    float s = 0.f;
    for (int v = 0; v < NVT; ++v) s += partials[(size_t)v * M_TOK + token];
    logp[token] = zt[token] - logf(s);
}

// -------- final SimPO scalar ----------------------------------------------
__global__ void __launch_bounds__(512) loss_kernel(const float* __restrict__ logp,
                                                   const int* __restrict__ target,
                                                   float* __restrict__ out) {
    __shared__ float ss[8], sc[8];
    int wid = threadIdx.x >> 6, lane = threadIdx.x & 63;
    float s = 0.f, cnt = 0.f;
    #pragma unroll
    for (int j = 0; j < 8; ++j) {
        int token = wid * 512 + lane + j * 64;
        if (target[token] != IGNORE_INDEX) { s += logp[token]; cnt += 1.f; }
    }
    #pragma unroll
    for (int m = 1; m < 64; m <<= 1) {
        s += __shfl_xor(s, m, 64);
        cnt += __shfl_xor(cnt, m, 64);
    }
    if (lane == 0) { ss[wid] = s; sc[wid] = cnt; }
    __syncthreads();
    if (threadIdx.x == 0) {
        float csum = 0.f, ccnt = 0.f;
        for (int b = 0; b < 4; ++b) { csum += ss[b]; ccnt += sc[b]; }
        float nll = -csum / ccnt;
        float pref = 0.f;
        for (int b = 0; b < 4; ++b) {
            float d = BETA_ * (ss[b] / sc[b] - ss[b + 4] / sc[b + 4]) - GAMMA_;
            float sp = (d > 0.f) ? log1pf(expf(-d)) : (-d + log1pf(expf(d)));
            pref += sp;
        }
        pref *= 0.25f;
        out[0] = nll + pref;
    }
}

// ---------------------------------------------------------------------------
extern "C" void kernel_launch(void* const* d_in, const int* in_sizes, int n_in,
                              void* d_out, int out_size, void* d_ws, size_t ws_size,
                              hipStream_t stream) {
    const float* W    = (const float*)d_in[0];
    const float* X    = (const float*)d_in[1];
    const int* target = (const int*)d_in[2];
    const float* bias = (const float*)d_in[3];
    float* out = (float*)d_out;
    char* ws = (char*)d_ws;

    // workspace layout (16B aligned), ~150 MB total (within round-1 footprint)
    unsigned short* Wb = (unsigned short*)(ws);                    // 131,072,000 B
    unsigned short* Xb = (unsigned short*)(ws + 131072000);        //  16,777,216 B
    float* partials    = (float*)(ws + 147849216);                 //   2,048,000 B
    float* zt          = (float*)(ws + 149897216);                 //      16,384 B
    float* logp        = (float*)(ws + 149913600);                 //      16,384 B

    cvt_kernel<<<dim3(64000), 256, 0, stream>>>(W, Wb);
    cvt_kernel<<<dim3(8192), 256, 0, stream>>>(X, Xb);
    zt_kernel<<<dim3(1024), 256, 0, stream>>>(X, W, bias, target, zt);
    gemm_lse_kernel<<<dim3(NMT * NVT), 512, 0, stream>>>(Xb, Wb, bias, partials);
    lse_kernel<<<dim3(16), 256, 0, stream>>>(partials, zt, logp);
    loss_kernel<<<dim3(1), 512, 0, stream>>>(logp, target, out);
}

// Round 4
// 589.855 us; speedup vs baseline: 1.1978x; 1.0412x over previous
//
#include <hip/hip_runtime.h>

// ---------------------------------------------------------------------------
// Fused Linear + SimPO loss on MI355X (gfx950)
// M = 4096 tokens, V = 32000, K = 2048
// GEMM: 256x256 tile, BK=64, 8 waves, 8-phase schedule, counted vmcnt,
// T2 LDS swizzle, T5 setprio, fused sum-exp epilogue.
// Round-4 fix: swizzle function for 64B-row geometry is (row>>1)&3, not row&3
// (row parity already selects the 16-bank half; the XOR must vary across
// row PAIRS to spread the 8-lane phase group over all 8 bank quads).
// ---------------------------------------------------------------------------

typedef short bf16x8 __attribute__((ext_vector_type(8)));
typedef float f32x4 __attribute__((ext_vector_type(4)));

#define IGNORE_INDEX (-100)
#define BETA_ 0.1f
#define GAMMA_ 0.5f

#define M_TOK 4096
#define V_DIM 32000
#define K_DIM 2048
#define NVT 125          // V / 256
#define NMT 16           // M / 256
#define NT  32           // K / 64  (K-tiles)

__device__ inline unsigned short f2bf(float f) {   // RNE fp32 -> bf16
    unsigned u = __float_as_uint(f);
    return (unsigned short)((u + 0x7FFFu + ((u >> 16) & 1u)) >> 16);
}

// -------- fp32 -> bf16 conversion ------------------------------------------
__global__ void __launch_bounds__(256) cvt_kernel(const float* __restrict__ src,
                                                  unsigned short* __restrict__ dst) {
    size_t i = ((size_t)blockIdx.x * 256 + threadIdx.x) * 4;
    float4 v = *reinterpret_cast<const float4*>(src + i);
    ushort4 o;
    o.x = f2bf(v.x); o.y = f2bf(v.y); o.z = f2bf(v.z); o.w = f2bf(v.w);
    *reinterpret_cast<ushort4*>(dst + i) = o;
}

// -------- exact fp32 target logit: one wave per token ----------------------
__global__ void __launch_bounds__(256) zt_kernel(const float* __restrict__ X,
                                                 const float* __restrict__ W,
                                                 const float* __restrict__ bias,
                                                 const int* __restrict__ target,
                                                 float* __restrict__ zt) {
    int token = blockIdx.x * 4 + (threadIdx.x >> 6);
    int lane = threadIdx.x & 63;
    int t = target[token];
    int tt = (t < 0) ? 0 : t;
    const float4* xr = reinterpret_cast<const float4*>(X + (size_t)token * K_DIM);
    const float4* wr = reinterpret_cast<const float4*>(W + (size_t)tt * K_DIM);
    float s = 0.f;
    #pragma unroll
    for (int j = 0; j < 8; ++j) {
        float4 a = xr[lane + j * 64];
        float4 b = wr[lane + j * 64];
        s += a.x * b.x + a.y * b.y + a.z * b.z + a.w * b.w;
    }
    #pragma unroll
    for (int m = 1; m < 64; m <<= 1) s += __shfl_xor(s, m, 64);
    if (lane == 0) zt[token] = s + bias[tt];
}

// -------- 256^2 8-phase bf16 GEMM with fused sum-exp epilogue --------------
// LDS per buffer (stride 65536): A_ks0 @0, A_ks1 @16384, B_ks0 @32768,
// B_ks1 @49152. Region = [256 rows][32 k-elems] bf16, row stride 64B.
// Swizzle: 16B slot c of row holds global k-slot (c ^ ((row>>1)&3)).
#define GLL(g, l) __builtin_amdgcn_global_load_lds( \
    (const __attribute__((address_space(1))) void*)(g), \
    (__attribute__((address_space(3))) void*)(l), 16, 0, 0)

__global__ void __launch_bounds__(512, 2) gemm_lse_kernel(
    const unsigned short* __restrict__ Xb,   // [4096][2048] bf16
    const unsigned short* __restrict__ Wb,   // [32000][2048] bf16
    const float* __restrict__ bias,          // [32000]
    float* __restrict__ partials) {          // [NVT][4096] sum-exp partials
    __shared__ char lds[131072];

    const int tid = threadIdx.x;
    const int wid = tid >> 6;
    const int lane = tid & 63;
    const int r = lane & 15, g = lane >> 4;
    const int wm = wid >> 2, wn = wid & 3;

    // bijective XCD-chunked swizzle: 2000 = 8 * 250, mt fastest inside chunk
    int nb = (blockIdx.x & 7) * 250 + (blockIdx.x >> 3);
    const int vt = nb >> 4;
    const int mt = nb & 15;

    // staging: thread covers row (tid>>2) (+128 for *S1), 16B slot tid&3,
    // inverse-swizzled source slot = (tid&3) ^ ((row>>1)&3)
    const int srow = tid >> 2;
    const int scol = ((tid & 3) ^ ((srow >> 1) & 3)) * 8;
    const unsigned short* aS0 = Xb + (size_t)(mt * 256 + srow) * K_DIM + scol;
    const unsigned short* aS1 = aS0 + (size_t)128 * K_DIM;
    const unsigned short* bS0 = Wb + (size_t)(vt * 256 + srow) * K_DIM + scol;
    const unsigned short* bS1 = bS0 + (size_t)128 * K_DIM;
    // dedicated ks1 pointers (+32 elems), laundered so the compiler cannot
    // fold the +64B into a global_load_lds offset immediate
    const unsigned short* aS0k = aS0 + 32;
    const unsigned short* aS1k = aS1 + 32;
    const unsigned short* bS0k = bS0 + 32;
    const unsigned short* bS1k = bS1 + 32;
    asm volatile("" : "+v"(aS0k), "+v"(aS1k), "+v"(bS0k), "+v"(bS1k));

    char* sbase = lds + wid * 1024;          // wave-uniform staging base
    // swizzled ds_read per-lane byte offsets ((row>>1)&3 == (r>>1)&3 since
    // wm*128, wn*64, mf*16, nfb*16 are all multiples of 16)
    const int vA = (wm * 128 + r) * 64 + ((g ^ ((r >> 1) & 3)) << 4);
    const int vB = (wn * 64 + r) * 64 + ((g ^ ((r >> 1) & 3)) << 4);

    f32x4 acc[8][4] = {};
    bf16x8 af[8], b0, b1;
    int pb = 0;

    // ---- prologue: tile0 (all 4 regions) into buf0, tile1 ks0 into buf1 ----
    GLL(aS0, sbase + 0);              GLL(aS1, sbase + 8192);
    GLL(bS0, sbase + 32768);          GLL(bS1, sbase + 32768 + 8192);
    GLL(aS0k, sbase + 16384);         GLL(aS1k, sbase + 16384 + 8192);
    GLL(bS0k, sbase + 49152);         GLL(bS1k, sbase + 49152 + 8192);
    aS0 += 64; aS1 += 64; bS0 += 64; bS1 += 64;
    aS0k += 64; aS1k += 64; bS0k += 64; bS1k += 64;
    GLL(aS0, sbase + 65536);          GLL(aS1, sbase + 65536 + 8192);
    GLL(bS0, sbase + 65536 + 32768);  GLL(bS1, sbase + 65536 + 32768 + 8192);
    asm volatile("s_waitcnt vmcnt(4)" ::: "memory");
    __builtin_amdgcn_s_barrier();

#define PH_READS_A(ks) \
    _Pragma("unroll") \
    for (int mf = 0; mf < 8; ++mf) \
        af[mf] = *(const bf16x8*)(lds + pb + vA + (ks) * 16384 + mf * 1024);

#define PH_READS_B(ks, nfb) \
    b0 = *(const bf16x8*)(lds + pb + vB + 32768 + (ks) * 16384 + (nfb) * 1024); \
    b1 = *(const bf16x8*)(lds + pb + vB + 32768 + (ks) * 16384 + ((nfb) + 1) * 1024);

#define PH_MFMA(nfb) \
    __builtin_amdgcn_s_setprio(1); \
    _Pragma("unroll") \
    for (int mf = 0; mf < 8; ++mf) { \
        acc[mf][(nfb)]     = __builtin_amdgcn_mfma_f32_16x16x32_bf16(af[mf], b0, acc[mf][(nfb)], 0, 0, 0); \
        acc[mf][(nfb) + 1] = __builtin_amdgcn_mfma_f32_16x16x32_bf16(af[mf], b1, acc[mf][(nfb) + 1], 0, 0, 0); \
    } \
    __builtin_amdgcn_s_setprio(0);

#define LGKM0 asm volatile("s_waitcnt lgkmcnt(0)" ::: "memory")

// Per K-tile body. I12: stage (t+1) ks1 into other buffer.
// I34: stage (t+2) ks0 into current buffer. DRAIN_STMT at end of P4.
#define KBODY(I12, I34, DRAIN_STMT) do { \
    char* cb = sbase + pb; \
    char* ob = sbase + (pb ^ 65536); \
    /* P1 */ \
    PH_READS_A(0); PH_READS_B(0, 0); \
    if (I12) { GLL(aS0k, ob + 16384); GLL(aS1k, ob + 16384 + 8192); } \
    __builtin_amdgcn_s_barrier(); \
    LGKM0; \
    PH_MFMA(0); \
    __builtin_amdgcn_s_barrier(); \
    /* P2 */ \
    PH_READS_B(0, 2); \
    if (I12) { GLL(bS0k, ob + 49152); GLL(bS1k, ob + 49152 + 8192); } \
    __builtin_amdgcn_s_barrier(); \
    LGKM0; \
    PH_MFMA(2); \
    __builtin_amdgcn_s_barrier(); \
    aS0 += 64; aS1 += 64; bS0 += 64; bS1 += 64; \
    aS0k += 64; aS1k += 64; bS0k += 64; bS1k += 64; \
    /* P3 */ \
    PH_READS_A(1); PH_READS_B(1, 0); \
    if (I34) { GLL(aS0, cb); GLL(aS1, cb + 8192); } \
    __builtin_amdgcn_s_barrier(); \
    LGKM0; \
    PH_MFMA(0); \
    __builtin_amdgcn_s_barrier(); \
    /* P4 */ \
    PH_READS_B(1, 2); \
    if (I34) { GLL(bS0, cb + 32768); GLL(bS1, cb + 32768 + 8192); } \
    __builtin_amdgcn_s_barrier(); \
    LGKM0; \
    PH_MFMA(2); \
    DRAIN_STMT; \
    __builtin_amdgcn_s_barrier(); \
    pb ^= 65536; \
} while (0)

    #pragma unroll 1
    for (int t = 0; t < NT - 2; ++t)
        KBODY(1, 1, asm volatile("s_waitcnt vmcnt(4)" ::: "memory"));
    KBODY(1, 0, asm volatile("s_waitcnt vmcnt(0)" ::: "memory"));
    KBODY(0, 0, (void)0);

    // ---- epilogue: bias + exp + row-sum over 256 cols --------------------
    float bb[4];
    #pragma unroll
    for (int nf = 0; nf < 4; ++nf)
        bb[nf] = bias[vt * 256 + wn * 64 + nf * 16 + r];

    __syncthreads();
    float* red = reinterpret_cast<float*>(lds);  // [4 wn][256 rows]
    #pragma unroll
    for (int mf = 0; mf < 8; ++mf) {
        #pragma unroll
        for (int i = 0; i < 4; ++i) {
            float s = 0.f;
            #pragma unroll
            for (int nf = 0; nf < 4; ++nf)
                s += __expf(acc[mf][nf][i] + bb[nf]);
            s += __shfl_xor(s, 1, 64);
            s += __shfl_xor(s, 2, 64);
            s += __shfl_xor(s, 4, 64);
            s += __shfl_xor(s, 8, 64);
            if (r == 0) red[wn * 256 + wm * 128 + mf * 16 + g * 4 + i] = s;
        }
    }
    __syncthreads();
    if (tid < 256) {
        float tot = red[tid] + red[256 + tid] + red[512 + tid] + red[768 + tid];
        partials[(size_t)vt * M_TOK + mt * 256 + tid] = tot;
    }
}

// -------- combine partials -> per-token logp -------------------------------
__global__ void __launch_bounds__(256) lse_kernel(const float* __restrict__ partials,
                                                  const float* __restrict__ zt,
                                                  float* __restrict__ logp) {
    int token = blockIdx.x * 256 + threadIdx.x;
    float s = 0.f;
    for (int v = 0; v < NVT; ++v) s += partials[(size_t)v * M_TOK + token];
    logp[token] = zt[token] - logf(s);
}

// -------- final SimPO scalar ----------------------------------------------
__global__ void __launch_bounds__(512) loss_kernel(const float* __restrict__ logp,
                                                   const int* __restrict__ target,
                                                   float* __restrict__ out) {
    __shared__ float ss[8], sc[8];
    int wid = threadIdx.x >> 6, lane = threadIdx.x & 63;
    float s = 0.f, cnt = 0.f;
    #pragma unroll
    for (int j = 0; j < 8; ++j) {
        int token = wid * 512 + lane + j * 64;
        if (target[token] != IGNORE_INDEX) { s += logp[token]; cnt += 1.f; }
    }
    #pragma unroll
    for (int m = 1; m < 64; m <<= 1) {
        s += __shfl_xor(s, m, 64);
        cnt += __shfl_xor(cnt, m, 64);
    }
    if (lane == 0) { ss[wid] = s; sc[wid] = cnt; }
    __syncthreads();
    if (threadIdx.x == 0) {
        float csum = 0.f, ccnt = 0.f;
        for (int b = 0; b < 4; ++b) { csum += ss[b]; ccnt += sc[b]; }
        float nll = -csum / ccnt;
        float pref = 0.f;
        for (int b = 0; b < 4; ++b) {
            float d = BETA_ * (ss[b] / sc[b] - ss[b + 4] / sc[b + 4]) - GAMMA_;
            float sp = (d > 0.f) ? log1pf(expf(-d)) : (-d + log1pf(expf(d)));
            pref += sp;
        }
        pref *= 0.25f;
        out[0] = nll + pref;
    }
}

// ---------------------------------------------------------------------------
extern "C" void kernel_launch(void* const* d_in, const int* in_sizes, int n_in,
                              void* d_out, int out_size, void* d_ws, size_t ws_size,
                              hipStream_t stream) {
    const float* W    = (const float*)d_in[0];
    const float* X    = (const float*)d_in[1];
    const int* target = (const int*)d_in[2];
    const float* bias = (const float*)d_in[3];
    float* out = (float*)d_out;
    char* ws = (char*)d_ws;

    // workspace layout (16B aligned), ~150 MB total
    unsigned short* Wb = (unsigned short*)(ws);                    // 131,072,000 B
    unsigned short* Xb = (unsigned short*)(ws + 131072000);        //  16,777,216 B
    float* partials    = (float*)(ws + 147849216);                 //   2,048,000 B
    float* zt          = (float*)(ws + 149897216);                 //      16,384 B
    float* logp        = (float*)(ws + 149913600);                 //      16,384 B

    cvt_kernel<<<dim3(64000), 256, 0, stream>>>(W, Wb);
    cvt_kernel<<<dim3(8192), 256, 0, stream>>>(X, Xb);
    zt_kernel<<<dim3(1024), 256, 0, stream>>>(X, W, bias, target, zt);
    gemm_lse_kernel<<<dim3(NMT * NVT), 512, 0, stream>>>(Xb, Wb, bias, partials);
    lse_kernel<<<dim3(16), 256, 0, stream>>>(partials, zt, logp);
    loss_kernel<<<dim3(1), 512, 0, stream>>>(logp, target, out);
}

// Round 5
// 581.495 us; speedup vs baseline: 1.2150x; 1.0144x over previous
//
#include <hip/hip_runtime.h>

// ---------------------------------------------------------------------------
// Fused Linear + SimPO loss on MI355X (gfx950)
// M = 4096 tokens, V = 32000, K = 2048
// GEMM: 256x256 tile, BK=64, 8 waves, 4-phase/K-tile schedule with ONE
// barrier per phase (reads+GLL pre-barrier, MFMA post-barrier), counted
// vmcnt, T2 LDS swizzle ((row>>1)&3), T5 setprio, fused sum-exp epilogue.
// Round-5: removed post-MFMA barriers + explicit lgkmcnt(0) -> compiler
// staggers lgkmcnt per operand; reads/GLL of phase k+1 overlap MFMA of k.
// ---------------------------------------------------------------------------

typedef short bf16x8 __attribute__((ext_vector_type(8)));
typedef float f32x4 __attribute__((ext_vector_type(4)));

#define IGNORE_INDEX (-100)
#define BETA_ 0.1f
#define GAMMA_ 0.5f

#define M_TOK 4096
#define V_DIM 32000
#define K_DIM 2048
#define NVT 125          // V / 256
#define NMT 16           // M / 256
#define NT  32           // K / 64  (K-tiles)

__device__ inline unsigned short f2bf(float f) {   // RNE fp32 -> bf16
    unsigned u = __float_as_uint(f);
    return (unsigned short)((u + 0x7FFFu + ((u >> 16) & 1u)) >> 16);
}

// -------- fp32 -> bf16 conversion ------------------------------------------
__global__ void __launch_bounds__(256) cvt_kernel(const float* __restrict__ src,
                                                  unsigned short* __restrict__ dst) {
    size_t i = ((size_t)blockIdx.x * 256 + threadIdx.x) * 4;
    float4 v = *reinterpret_cast<const float4*>(src + i);
    ushort4 o;
    o.x = f2bf(v.x); o.y = f2bf(v.y); o.z = f2bf(v.z); o.w = f2bf(v.w);
    *reinterpret_cast<ushort4*>(dst + i) = o;
}

// -------- exact fp32 target logit: one wave per token ----------------------
__global__ void __launch_bounds__(256) zt_kernel(const float* __restrict__ X,
                                                 const float* __restrict__ W,
                                                 const float* __restrict__ bias,
                                                 const int* __restrict__ target,
                                                 float* __restrict__ zt) {
    int token = blockIdx.x * 4 + (threadIdx.x >> 6);
    int lane = threadIdx.x & 63;
    int t = target[token];
    int tt = (t < 0) ? 0 : t;
    const float4* xr = reinterpret_cast<const float4*>(X + (size_t)token * K_DIM);
    const float4* wr = reinterpret_cast<const float4*>(W + (size_t)tt * K_DIM);
    float s = 0.f;
    #pragma unroll
    for (int j = 0; j < 8; ++j) {
        float4 a = xr[lane + j * 64];
        float4 b = wr[lane + j * 64];
        s += a.x * b.x + a.y * b.y + a.z * b.z + a.w * b.w;
    }
    #pragma unroll
    for (int m = 1; m < 64; m <<= 1) s += __shfl_xor(s, m, 64);
    if (lane == 0) zt[token] = s + bias[tt];
}

// -------- 256^2 4-phase bf16 GEMM with fused sum-exp epilogue --------------
// LDS per buffer (stride 65536): A_ks0 @0, A_ks1 @16384, B_ks0 @32768,
// B_ks1 @49152. Region = [256 rows][32 k-elems] bf16, row stride 64B.
// Swizzle: 16B slot c of row holds global k-slot (c ^ ((row>>1)&3)).
#define GLL(g, l) __builtin_amdgcn_global_load_lds( \
    (const __attribute__((address_space(1))) void*)(g), \
    (__attribute__((address_space(3))) void*)(l), 16, 0, 0)

__global__ void __launch_bounds__(512, 2) gemm_lse_kernel(
    const unsigned short* __restrict__ Xb,   // [4096][2048] bf16
    const unsigned short* __restrict__ Wb,   // [32000][2048] bf16
    const float* __restrict__ bias,          // [32000]
    float* __restrict__ partials) {          // [NVT][4096] sum-exp partials
    __shared__ char lds[131072];

    const int tid = threadIdx.x;
    const int wid = tid >> 6;
    const int lane = tid & 63;
    const int r = lane & 15, g = lane >> 4;
    const int wm = wid >> 2, wn = wid & 3;

    // bijective XCD-chunked swizzle: 2000 = 8 * 250, mt fastest inside chunk
    int nb = (blockIdx.x & 7) * 250 + (blockIdx.x >> 3);
    const int vt = nb >> 4;
    const int mt = nb & 15;

    // staging: thread covers row (tid>>2) (+128 for *S1), 16B slot tid&3,
    // inverse-swizzled source slot = (tid&3) ^ ((row>>1)&3)
    const int srow = tid >> 2;
    const int scol = ((tid & 3) ^ ((srow >> 1) & 3)) * 8;
    const unsigned short* aS0 = Xb + (size_t)(mt * 256 + srow) * K_DIM + scol;
    const unsigned short* aS1 = aS0 + (size_t)128 * K_DIM;
    const unsigned short* bS0 = Wb + (size_t)(vt * 256 + srow) * K_DIM + scol;
    const unsigned short* bS1 = bS0 + (size_t)128 * K_DIM;
    // dedicated ks1 pointers (+32 elems), laundered so the compiler cannot
    // fold the +64B into a global_load_lds offset immediate
    const unsigned short* aS0k = aS0 + 32;
    const unsigned short* aS1k = aS1 + 32;
    const unsigned short* bS0k = bS0 + 32;
    const unsigned short* bS1k = bS1 + 32;
    asm volatile("" : "+v"(aS0k), "+v"(aS1k), "+v"(bS0k), "+v"(bS1k));

    char* sbase = lds + wid * 1024;          // wave-uniform staging base
    // swizzled ds_read per-lane byte offsets ((row>>1)&3 == (r>>1)&3 since
    // wm*128, wn*64, mf*16, nfb*16 are all multiples of 16)
    const int vA = (wm * 128 + r) * 64 + ((g ^ ((r >> 1) & 3)) << 4);
    const int vB = (wn * 64 + r) * 64 + ((g ^ ((r >> 1) & 3)) << 4);

    f32x4 acc[8][4] = {};
    bf16x8 af[8], b0, b1;
    int pb = 0;

    // ---- prologue: tile0 (all 4 regions) into buf0, tile1 ks0 into buf1 ----
    GLL(aS0, sbase + 0);              GLL(aS1, sbase + 8192);
    GLL(bS0, sbase + 32768);          GLL(bS1, sbase + 32768 + 8192);
    GLL(aS0k, sbase + 16384);         GLL(aS1k, sbase + 16384 + 8192);
    GLL(bS0k, sbase + 49152);         GLL(bS1k, sbase + 49152 + 8192);
    aS0 += 64; aS1 += 64; bS0 += 64; bS1 += 64;
    aS0k += 64; aS1k += 64; bS0k += 64; bS1k += 64;
    GLL(aS0, sbase + 65536);          GLL(aS1, sbase + 65536 + 8192);
    GLL(bS0, sbase + 65536 + 32768);  GLL(bS1, sbase + 65536 + 32768 + 8192);
    asm volatile("s_waitcnt vmcnt(4)" ::: "memory");
    __builtin_amdgcn_s_barrier();
    asm volatile("" ::: "memory");

// barrier wrapped in compiler memory fences: pins pre-barrier LDS reads /
// GLL issues on their side; no hardware wait emitted (raw s_barrier).
#define BARX do { \
    asm volatile("" ::: "memory"); \
    __builtin_amdgcn_s_barrier(); \
    asm volatile("" ::: "memory"); \
} while (0)

#define PH_READS_A(ks) \
    _Pragma("unroll") \
    for (int mf = 0; mf < 8; ++mf) \
        af[mf] = *(const bf16x8*)(lds + pb + vA + (ks) * 16384 + mf * 1024);

#define PH_READS_B(ks, nfb) \
    b0 = *(const bf16x8*)(lds + pb + vB + 32768 + (ks) * 16384 + (nfb) * 1024); \
    b1 = *(const bf16x8*)(lds + pb + vB + 32768 + (ks) * 16384 + ((nfb) + 1) * 1024);

#define PH_MFMA(nfb) \
    __builtin_amdgcn_s_setprio(1); \
    _Pragma("unroll") \
    for (int mf = 0; mf < 8; ++mf) { \
        acc[mf][(nfb)]     = __builtin_amdgcn_mfma_f32_16x16x32_bf16(af[mf], b0, acc[mf][(nfb)], 0, 0, 0); \
        acc[mf][(nfb) + 1] = __builtin_amdgcn_mfma_f32_16x16x32_bf16(af[mf], b1, acc[mf][(nfb) + 1], 0, 0, 0); \
    } \
    __builtin_amdgcn_s_setprio(0);

// Per K-tile: 4 phases, ONE barrier each (before MFMA). GLL issued at phase
// start (issue-early); ds_reads before barrier; no explicit lgkmcnt — the
// compiler staggers waits per MFMA operand so reads drain under MFMA.
// I12: stage (t+1) ks1 into other buffer. I34: stage (t+2) ks0 into current.
// DRAIN_STMT runs just before P4's barrier (drain, then publish).
#define KBODY(I12, I34, DRAIN_STMT) do { \
    char* cb = sbase + pb; \
    char* ob = sbase + (pb ^ 65536); \
    /* P1 */ \
    if (I12) { GLL(aS0k, ob + 16384); GLL(aS1k, ob + 16384 + 8192); } \
    PH_READS_B(0, 0); PH_READS_A(0); \
    BARX; \
    PH_MFMA(0); \
    /* P2 */ \
    if (I12) { GLL(bS0k, ob + 49152); GLL(bS1k, ob + 49152 + 8192); } \
    PH_READS_B(0, 2); \
    BARX; \
    PH_MFMA(2); \
    aS0 += 64; aS1 += 64; bS0 += 64; bS1 += 64; \
    aS0k += 64; aS1k += 64; bS0k += 64; bS1k += 64; \
    /* P3 */ \
    if (I34) { GLL(aS0, cb); GLL(aS1, cb + 8192); } \
    PH_READS_B(1, 0); PH_READS_A(1); \
    BARX; \
    PH_MFMA(0); \
    /* P4 */ \
    if (I34) { GLL(bS0, cb + 32768); GLL(bS1, cb + 32768 + 8192); } \
    PH_READS_B(1, 2); \
    DRAIN_STMT; \
    BARX; \
    PH_MFMA(2); \
    pb ^= 65536; \
} while (0)

    #pragma unroll 1
    for (int t = 0; t < NT - 2; ++t)
        KBODY(1, 1, asm volatile("s_waitcnt vmcnt(4)" ::: "memory"));
    KBODY(1, 0, asm volatile("s_waitcnt vmcnt(0)" ::: "memory"));
    KBODY(0, 0, (void)0);

    // ---- epilogue: bias + exp + row-sum over 256 cols --------------------
    float bb[4];
    #pragma unroll
    for (int nf = 0; nf < 4; ++nf)
        bb[nf] = bias[vt * 256 + wn * 64 + nf * 16 + r];

    __syncthreads();
    float* red = reinterpret_cast<float*>(lds);  // [4 wn][256 rows]
    #pragma unroll
    for (int mf = 0; mf < 8; ++mf) {
        #pragma unroll
        for (int i = 0; i < 4; ++i) {
            float s = 0.f;
            #pragma unroll
            for (int nf = 0; nf < 4; ++nf)
                s += __expf(acc[mf][nf][i] + bb[nf]);
            s += __shfl_xor(s, 1, 64);
            s += __shfl_xor(s, 2, 64);
            s += __shfl_xor(s, 4, 64);
            s += __shfl_xor(s, 8, 64);
            if (r == 0) red[wn * 256 + wm * 128 + mf * 16 + g * 4 + i] = s;
        }
    }
    __syncthreads();
    if (tid < 256) {
        float tot = red[tid] + red[256 + tid] + red[512 + tid] + red[768 + tid];
        partials[(size_t)vt * M_TOK + mt * 256 + tid] = tot;
    }
}

// -------- combine partials -> per-token logp -------------------------------
__global__ void __launch_bounds__(256) lse_kernel(const float* __restrict__ partials,
                                                  const float* __restrict__ zt,
                                                  float* __restrict__ logp) {
    int token = blockIdx.x * 256 + threadIdx.x;
    float s = 0.f;
    for (int v = 0; v < NVT; ++v) s += partials[(size_t)v * M_TOK + token];
    logp[token] = zt[token] - logf(s);
}

// -------- final SimPO scalar ----------------------------------------------
__global__ void __launch_bounds__(512) loss_kernel(const float* __restrict__ logp,
                                                   const int* __restrict__ target,
                                                   float* __restrict__ out) {
    __shared__ float ss[8], sc[8];
    int wid = threadIdx.x >> 6, lane = threadIdx.x & 63;
    float s = 0.f, cnt = 0.f;
    #pragma unroll
    for (int j = 0; j < 8; ++j) {
        int token = wid * 512 + lane + j * 64;
        if (target[token] != IGNORE_INDEX) { s += logp[token]; cnt += 1.f; }
    }
    #pragma unroll
    for (int m = 1; m < 64; m <<= 1) {
        s += __shfl_xor(s, m, 64);
        cnt += __shfl_xor(cnt, m, 64);
    }
    if (lane == 0) { ss[wid] = s; sc[wid] = cnt; }
    __syncthreads();
    if (threadIdx.x == 0) {
        float csum = 0.f, ccnt = 0.f;
        for (int b = 0; b < 4; ++b) { csum += ss[b]; ccnt += sc[b]; }
        float nll = -csum / ccnt;
        float pref = 0.f;
        for (int b = 0; b < 4; ++b) {
            float d = BETA_ * (ss[b] / sc[b] - ss[b + 4] / sc[b + 4]) - GAMMA_;
            float sp = (d > 0.f) ? log1pf(expf(-d)) : (-d + log1pf(expf(d)));
            pref += sp;
        }
        pref *= 0.25f;
        out[0] = nll + pref;
    }
}

// ---------------------------------------------------------------------------
extern "C" void kernel_launch(void* const* d_in, const int* in_sizes, int n_in,
                              void* d_out, int out_size, void* d_ws, size_t ws_size,
                              hipStream_t stream) {
    const float* W    = (const float*)d_in[0];
    const float* X    = (const float*)d_in[1];
    const int* target = (const int*)d_in[2];
    const float* bias = (const float*)d_in[3];
    float* out = (float*)d_out;
    char* ws = (char*)d_ws;

    // workspace layout (16B aligned), ~150 MB total
    unsigned short* Wb = (unsigned short*)(ws);                    // 131,072,000 B
    unsigned short* Xb = (unsigned short*)(ws + 131072000);        //  16,777,216 B
    float* partials    = (float*)(ws + 147849216);                 //   2,048,000 B
    float* zt          = (float*)(ws + 149897216);                 //      16,384 B
    float* logp        = (float*)(ws + 149913600);                 //      16,384 B

    cvt_kernel<<<dim3(64000), 256, 0, stream>>>(W, Wb);
    cvt_kernel<<<dim3(8192), 256, 0, stream>>>(X, Xb);
    zt_kernel<<<dim3(1024), 256, 0, stream>>>(X, W, bias, target, zt);
    gemm_lse_kernel<<<dim3(NMT * NVT), 512, 0, stream>>>(Xb, Wb, bias, partials);
    lse_kernel<<<dim3(16), 256, 0, stream>>>(partials, zt, logp);
    loss_kernel<<<dim3(1), 512, 0, stream>>>(logp, target, out);
}

// Round 6
// 581.305 us; speedup vs baseline: 1.2154x; 1.0003x over previous
//
#include <hip/hip_runtime.h>

// ---------------------------------------------------------------------------
// Fused Linear + SimPO loss on MI355X (gfx950)
// M = 4096 tokens, V = 32000, K = 2048
// GEMM: 256x256 tile, BK=64, 8 waves, 4 phases/K-tile, ONE barrier/phase,
// fragment REGISTER double-buffering (reads for phase k+1 overlap MFMA of k,
// disjoint register sets), GLL issued post-barrier, counted vmcnt(6) drains,
// T2 LDS swizzle ((row>>1)&3), T5 setprio, fused sum-exp epilogue.
// ---------------------------------------------------------------------------

typedef short bf16x8 __attribute__((ext_vector_type(8)));
typedef float f32x4 __attribute__((ext_vector_type(4)));

#define IGNORE_INDEX (-100)
#define BETA_ 0.1f
#define GAMMA_ 0.5f

#define M_TOK 4096
#define V_DIM 32000
#define K_DIM 2048
#define NVT 125          // V / 256
#define NMT 16           // M / 256
#define NT  32           // K / 64  (K-tiles)

__device__ inline unsigned short f2bf(float f) {   // RNE fp32 -> bf16
    unsigned u = __float_as_uint(f);
    return (unsigned short)((u + 0x7FFFu + ((u >> 16) & 1u)) >> 16);
}

// -------- fp32 -> bf16 conversion ------------------------------------------
__global__ void __launch_bounds__(256) cvt_kernel(const float* __restrict__ src,
                                                  unsigned short* __restrict__ dst) {
    size_t i = ((size_t)blockIdx.x * 256 + threadIdx.x) * 4;
    float4 v = *reinterpret_cast<const float4*>(src + i);
    ushort4 o;
    o.x = f2bf(v.x); o.y = f2bf(v.y); o.z = f2bf(v.z); o.w = f2bf(v.w);
    *reinterpret_cast<ushort4*>(dst + i) = o;
}

// -------- exact fp32 target logit: one wave per token ----------------------
__global__ void __launch_bounds__(256) zt_kernel(const float* __restrict__ X,
                                                 const float* __restrict__ W,
                                                 const float* __restrict__ bias,
                                                 const int* __restrict__ target,
                                                 float* __restrict__ zt) {
    int token = blockIdx.x * 4 + (threadIdx.x >> 6);
    int lane = threadIdx.x & 63;
    int t = target[token];
    int tt = (t < 0) ? 0 : t;
    const float4* xr = reinterpret_cast<const float4*>(X + (size_t)token * K_DIM);
    const float4* wr = reinterpret_cast<const float4*>(W + (size_t)tt * K_DIM);
    float s = 0.f;
    #pragma unroll
    for (int j = 0; j < 8; ++j) {
        float4 a = xr[lane + j * 64];
        float4 b = wr[lane + j * 64];
        s += a.x * b.x + a.y * b.y + a.z * b.z + a.w * b.w;
    }
    #pragma unroll
    for (int m = 1; m < 64; m <<= 1) s += __shfl_xor(s, m, 64);
    if (lane == 0) zt[token] = s + bias[tt];
}

// -------- 256^2 pipelined bf16 GEMM with fused sum-exp epilogue ------------
// LDS per buffer (stride 65536): A_ks0 @0, A_ks1 @16384, B_ks0 @32768,
// B_ks1 @49152. Region = [256 rows][32 k-elems] bf16, row stride 64B.
// Swizzle: 16B slot c of row holds global k-slot (c ^ ((row>>1)&3)).
#define GLL(g, l) __builtin_amdgcn_global_load_lds( \
    (const __attribute__((address_space(1))) void*)(g), \
    (__attribute__((address_space(3))) void*)(l), 16, 0, 0)

__global__ void __launch_bounds__(512, 2) gemm_lse_kernel(
    const unsigned short* __restrict__ Xb,   // [4096][2048] bf16
    const unsigned short* __restrict__ Wb,   // [32000][2048] bf16
    const float* __restrict__ bias,          // [32000]
    float* __restrict__ partials) {          // [NVT][4096] sum-exp partials
    __shared__ char lds[131072];

    const int tid = threadIdx.x;
    const int wid = tid >> 6;
    const int lane = tid & 63;
    const int r = lane & 15, g = lane >> 4;
    const int wm = wid >> 2, wn = wid & 3;

    // bijective XCD-chunked swizzle: 2000 = 8 * 250, mt fastest inside chunk
    int nb = (blockIdx.x & 7) * 250 + (blockIdx.x >> 3);
    const int vt = nb >> 4;
    const int mt = nb & 15;

    // staging: thread covers row (tid>>2) (+128 for *S1), 16B slot tid&3,
    // inverse-swizzled source slot = (tid&3) ^ ((row>>1)&3)
    const int srow = tid >> 2;
    const int scol = ((tid & 3) ^ ((srow >> 1) & 3)) * 8;
    const unsigned short* aS0 = Xb + (size_t)(mt * 256 + srow) * K_DIM + scol;
    const unsigned short* aS1 = aS0 + (size_t)128 * K_DIM;
    const unsigned short* bS0 = Wb + (size_t)(vt * 256 + srow) * K_DIM + scol;
    const unsigned short* bS1 = bS0 + (size_t)128 * K_DIM;
    // dedicated ks1 pointers (+32 elems), laundered so the compiler cannot
    // fold the +64B into a global_load_lds offset immediate
    const unsigned short* aS0k = aS0 + 32;
    const unsigned short* aS1k = aS1 + 32;
    const unsigned short* bS0k = bS0 + 32;
    const unsigned short* bS1k = bS1 + 32;
    asm volatile("" : "+v"(aS0k), "+v"(aS1k), "+v"(bS0k), "+v"(bS1k));

    char* sbase = lds + wid * 1024;          // wave-uniform staging base
    // swizzled ds_read per-lane byte offsets ((row>>1)&3 == (r>>1)&3 since
    // wm*128, wn*64, mf*16, nf*16 are all multiples of 16)
    const int vA = (wm * 128 + r) * 64 + ((g ^ ((r >> 1) & 3)) << 4);
    const int vB = (wn * 64 + r) * 64 + ((g ^ ((r >> 1) & 3)) << 4);

    f32x4 acc[8][4] = {};
    bf16x8 As0[4], As1[4], Bs0[4], Bs1[4];   // disjoint phase register sets
    int pb = 0;

    // ---- prologue: tile0 ks0+ks1 -> buf0, tile1 ks0 -> buf1 ---------------
    GLL(aS0, sbase + 0);              GLL(aS1, sbase + 8192);
    GLL(bS0, sbase + 32768);          GLL(bS1, sbase + 32768 + 8192);
    GLL(aS0k, sbase + 16384);         GLL(aS1k, sbase + 16384 + 8192);
    GLL(bS0k, sbase + 49152);         GLL(bS1k, sbase + 49152 + 8192);
    aS0 += 64; aS1 += 64; bS0 += 64; bS1 += 64;
    aS0k += 64; aS1k += 64; bS0k += 64; bS1k += 64;
    GLL(aS0, sbase + 65536);          GLL(aS1, sbase + 65536 + 8192);
    GLL(bS0, sbase + 65536 + 32768);  GLL(bS1, sbase + 65536 + 32768 + 8192);
    asm volatile("s_waitcnt vmcnt(8)" ::: "memory");   // tile0 ks0 complete
    __builtin_amdgcn_s_barrier();
    asm volatile("" ::: "memory");

#define BARX do { \
    asm volatile("" ::: "memory"); \
    __builtin_amdgcn_s_barrier(); \
    asm volatile("" ::: "memory"); \
} while (0)

#define RD_A(dst, ks, half) \
    _Pragma("unroll") \
    for (int j = 0; j < 4; ++j) \
        dst[j] = *(const bf16x8*)(lds + pb + vA + (ks) * 16384 + ((half) * 4 + j) * 1024);

#define RD_B(dst, ks) \
    _Pragma("unroll") \
    for (int n = 0; n < 4; ++n) \
        dst[n] = *(const bf16x8*)(lds + pb + 32768 + (ks) * 16384 + vB + n * 1024);

#define RD_A_OB(dst) \
    _Pragma("unroll") \
    for (int j = 0; j < 4; ++j) \
        dst[j] = *(const bf16x8*)(lds + (pb ^ 65536) + vA + j * 1024);

#define RD_B_OB(dst) \
    _Pragma("unroll") \
    for (int n = 0; n < 4; ++n) \
        dst[n] = *(const bf16x8*)(lds + (pb ^ 65536) + 32768 + vB + n * 1024);

#define MM(Aset, Bset, mb) \
    __builtin_amdgcn_s_setprio(1); \
    _Pragma("unroll") \
    for (int j = 0; j < 4; ++j) { \
        _Pragma("unroll") \
        for (int n = 0; n < 4; ++n) \
            acc[(mb) + j][n] = __builtin_amdgcn_mfma_f32_16x16x32_bf16( \
                Aset[j], Bset[n], acc[(mb) + j][n], 0, 0, 0); \
    } \
    __builtin_amdgcn_s_setprio(0);

#define VM6 asm volatile("s_waitcnt vmcnt(6)" ::: "memory")
#define VM4 asm volatile("s_waitcnt vmcnt(4)" ::: "memory")
#define VM0 asm volatile("s_waitcnt vmcnt(0)" ::: "memory")

// Phases per K-tile t (each: [drain]; BARX; GLL(post-barrier); reads for the
// NEXT phase into its disjoint register set; MFMA from regs read LAST phase):
//  ph1: Alo(ks0)xB(ks0)  reads: Ahi(ks0)        GLL: (t+1)ks1-A
//  ph2: Ahi(ks0)xB(ks0)  reads: B(ks1),Alo(ks1) GLL: (t+1)ks1-B   [D2 pre]
//  ph3: Alo(ks1)xB(ks1)  reads: Ahi(ks1)        GLL: (t+2)ks0-A
//  ph4: Ahi(ks1)xB(ks1)  reads: B,Alo(ks0,t+1 buf)GLL:(t+2)ks0-B  [D4 pre]
#define KBODY(S12, S34, D2S, D4S, RDNEXT) do { \
    char* cb = sbase + pb; \
    char* ob = sbase + (pb ^ 65536); \
    /* ph1 */ \
    BARX; \
    if (S12) { GLL(aS0k, ob + 16384); GLL(aS1k, ob + 16384 + 8192); } \
    RD_A(As1, 0, 1); \
    MM(As0, Bs0, 0); \
    /* ph2 */ \
    D2S; \
    BARX; \
    if (S12) { GLL(bS0k, ob + 49152); GLL(bS1k, ob + 49152 + 8192); } \
    RD_B(Bs1, 1); \
    RD_A(As0, 1, 0); \
    MM(As1, Bs0, 4); \
    aS0 += 64; aS1 += 64; bS0 += 64; bS1 += 64; \
    aS0k += 64; aS1k += 64; bS0k += 64; bS1k += 64; \
    /* ph3 */ \
    BARX; \
    if (S34) { GLL(aS0, cb); GLL(aS1, cb + 8192); } \
    RD_A(As1, 1, 1); \
    MM(As0, Bs1, 0); \
    /* ph4 */ \
    D4S; \
    BARX; \
    if (S34) { GLL(bS0, cb + 32768); GLL(bS1, cb + 32768 + 8192); } \
    if (RDNEXT) { RD_B_OB(Bs0); RD_A_OB(As0); } \
    MM(As1, Bs1, 4); \
    pb ^= 65536; \
} while (0)

    // initial reads for tile0 ph1 (post-publish-barrier): Alo(ks0) + B(ks0)
    RD_A(As0, 0, 0);
    RD_B(Bs0, 0);

    #pragma unroll 1
    for (int t = 0; t < NT - 2; ++t)
        KBODY(1, 1, VM6, VM6, 1);
    KBODY(1, 0, VM6, VM4, 1);        // t = 30: last ks1 stage, no ks0 stage
    KBODY(0, 0, VM0, (void)0, 0);    // t = 31: drain all, no stage, no reads

    // ---- epilogue: bias + exp + row-sum over 256 cols --------------------
    float bb[4];
    #pragma unroll
    for (int nf = 0; nf < 4; ++nf)
        bb[nf] = bias[vt * 256 + wn * 64 + nf * 16 + r];

    __syncthreads();
    float* red = reinterpret_cast<float*>(lds);  // [4 wn][256 rows]
    #pragma unroll
    for (int mf = 0; mf < 8; ++mf) {
        #pragma unroll
        for (int i = 0; i < 4; ++i) {
            float s = 0.f;
            #pragma unroll
            for (int nf = 0; nf < 4; ++nf)
                s += __expf(acc[mf][nf][i] + bb[nf]);
            s += __shfl_xor(s, 1, 64);
            s += __shfl_xor(s, 2, 64);
            s += __shfl_xor(s, 4, 64);
            s += __shfl_xor(s, 8, 64);
            if (r == 0) red[wn * 256 + wm * 128 + mf * 16 + g * 4 + i] = s;
        }
    }
    __syncthreads();
    if (tid < 256) {
        float tot = red[tid] + red[256 + tid] + red[512 + tid] + red[768 + tid];
        partials[(size_t)vt * M_TOK + mt * 256 + tid] = tot;
    }
}

// -------- combine partials -> per-token logp -------------------------------
__global__ void __launch_bounds__(256) lse_kernel(const float* __restrict__ partials,
                                                  const float* __restrict__ zt,
                                                  float* __restrict__ logp) {
    int token = blockIdx.x * 256 + threadIdx.x;
    float s = 0.f;
    for (int v = 0; v < NVT; ++v) s += partials[(size_t)v * M_TOK + token];
    logp[token] = zt[token] - logf(s);
}

// -------- final SimPO scalar ----------------------------------------------
__global__ void __launch_bounds__(512) loss_kernel(const float* __restrict__ logp,
                                                   const int* __restrict__ target,
                                                   float* __restrict__ out) {
    __shared__ float ss[8], sc[8];
    int wid = threadIdx.x >> 6, lane = threadIdx.x & 63;
    float s = 0.f, cnt = 0.f;
    #pragma unroll
    for (int j = 0; j < 8; ++j) {
        int token = wid * 512 + lane + j * 64;
        if (target[token] != IGNORE_INDEX) { s += logp[token]; cnt += 1.f; }
    }
    #pragma unroll
    for (int m = 1; m < 64; m <<= 1) {
        s += __shfl_xor(s, m, 64);
        cnt += __shfl_xor(cnt, m, 64);
    }
    if (lane == 0) { ss[wid] = s; sc[wid] = cnt; }
    __syncthreads();
    if (threadIdx.x == 0) {
        float csum = 0.f, ccnt = 0.f;
        for (int b = 0; b < 4; ++b) { csum += ss[b]; ccnt += sc[b]; }
        float nll = -csum / ccnt;
        float pref = 0.f;
        for (int b = 0; b < 4; ++b) {
            float d = BETA_ * (ss[b] / sc[b] - ss[b + 4] / sc[b + 4]) - GAMMA_;
            float sp = (d > 0.f) ? log1pf(expf(-d)) : (-d + log1pf(expf(d)));
            pref += sp;
        }
        pref *= 0.25f;
        out[0] = nll + pref;
    }
}

// ---------------------------------------------------------------------------
extern "C" void kernel_launch(void* const* d_in, const int* in_sizes, int n_in,
                              void* d_out, int out_size, void* d_ws, size_t ws_size,
                              hipStream_t stream) {
    const float* W    = (const float*)d_in[0];
    const float* X    = (const float*)d_in[1];
    const int* target = (const int*)d_in[2];
    const float* bias = (const float*)d_in[3];
    float* out = (float*)d_out;
    char* ws = (char*)d_ws;

    // workspace layout (16B aligned), ~150 MB total
    unsigned short* Wb = (unsigned short*)(ws);                    // 131,072,000 B
    unsigned short* Xb = (unsigned short*)(ws + 131072000);        //  16,777,216 B
    float* partials    = (float*)(ws + 147849216);                 //   2,048,000 B
    float* zt          = (float*)(ws + 149897216);                 //      16,384 B
    float* logp        = (float*)(ws + 149913600);                 //      16,384 B

    cvt_kernel<<<dim3(64000), 256, 0, stream>>>(W, Wb);
    cvt_kernel<<<dim3(8192), 256, 0, stream>>>(X, Xb);
    zt_kernel<<<dim3(1024), 256, 0, stream>>>(X, W, bias, target, zt);
    gemm_lse_kernel<<<dim3(NMT * NVT), 512, 0, stream>>>(Xb, Wb, bias, partials);
    lse_kernel<<<dim3(16), 256, 0, stream>>>(partials, zt, logp);
    loss_kernel<<<dim3(1), 512, 0, stream>>>(logp, target, out);
}